// Round 1
// baseline (360.213 us; speedup 1.0000x reference)
//
#include <hip/hip_runtime.h>
#include <hip/hip_bf16.h>

// StandardAttention: B=2, N=4096, D=512, H=8, HD=64, causal.
// Pipeline: convert/transpose -> QKV GEMM (bf16 MFMA) -> flash attention -> out GEMM.

typedef __bf16 bf16_t;
typedef __bf16 bf16x4 __attribute__((ext_vector_type(4)));
typedef __bf16 bf16x8 __attribute__((ext_vector_type(8)));
typedef float  f32x4  __attribute__((ext_vector_type(4)));

// ---------------- conversion kernels ----------------

__global__ void convert_f32_bf16(const float* __restrict__ in, bf16_t* __restrict__ out) {
    int i = blockIdx.x * 256 + threadIdx.x;       // one float4 per thread, exact grid
    float4 v = ((const float4*)in)[i];
    bf16x4 o;
    o[0] = (bf16_t)v.x; o[1] = (bf16_t)v.y; o[2] = (bf16_t)v.z; o[3] = (bf16_t)v.w;
    ((bf16x4*)out)[i] = o;
}

// in: [512][N] fp32 row-major -> out: [N][512] bf16 (transposed)
__global__ void transpose_convert(const float* __restrict__ in, bf16_t* __restrict__ out, int N) {
    int i = blockIdx.x * 256 + threadIdx.x;       // i over N*512, exact grid
    int n = i >> 9, k = i & 511;
    out[i] = (bf16_t)in[k * N + n];
}

// ---------------- GEMM: C[M,Ncols] = A[M,512] * Bt[Ncols,512]^T + bias ----------------
// MODE 0: QKV projection -> scatter into Q[BH][4096][64], K[BH][4096][64], Vt[BH][64][4096] (bf16)
// MODE 1: out projection -> Cout fp32 [M,512]

template <int MODE>
__global__ __launch_bounds__(256) void gemm_bt(
    const bf16_t* __restrict__ A, const bf16_t* __restrict__ Bt,
    const float* __restrict__ bias,
    bf16_t* __restrict__ Qg, bf16_t* __restrict__ Kg, bf16_t* __restrict__ Vt,
    float* __restrict__ Cout)
{
    __shared__ bf16_t As[128][72];   // +8 pad: breaks 16-way ds_read_b128 bank conflict
    __shared__ bf16_t Bs[128][72];
    const int tid  = threadIdx.x;
    const int wid  = tid >> 6, lane = tid & 63, l16 = lane & 15, quad = lane >> 4;
    const int wr   = (wid >> 1) * 64, wc = (wid & 1) * 64;
    const int m0   = blockIdx.y * 128, n0 = blockIdx.x * 128;

    f32x4 acc[4][4] = {};

    for (int kk = 0; kk < 512; kk += 64) {
        __syncthreads();
        // stage 128x64 bf16 tiles of A and Bt (8 chunks of 16B per row)
        #pragma unroll
        for (int i = 0; i < 4; ++i) {
            int c = tid + i * 256, row = c >> 3, col8 = (c & 7) * 8;
            *(uint4*)&As[row][col8] = *(const uint4*)(A  + (size_t)(m0 + row) * 512 + kk + col8);
            *(uint4*)&Bs[row][col8] = *(const uint4*)(Bt + (size_t)(n0 + row) * 512 + kk + col8);
        }
        __syncthreads();
        #pragma unroll
        for (int s = 0; s < 2; ++s) {
            bf16x8 a[4], b[4];
            #pragma unroll
            for (int i = 0; i < 4; ++i) a[i] = *(const bf16x8*)&As[wr + i * 16 + l16][s * 32 + quad * 8];
            #pragma unroll
            for (int j = 0; j < 4; ++j) b[j] = *(const bf16x8*)&Bs[wc + j * 16 + l16][s * 32 + quad * 8];
            #pragma unroll
            for (int i = 0; i < 4; ++i)
                #pragma unroll
                for (int j = 0; j < 4; ++j)
                    acc[i][j] = __builtin_amdgcn_mfma_f32_16x16x32_bf16(a[i], b[j], acc[i][j], 0, 0, 0);
        }
    }

    // epilogue: C/D layout col=lane&15, row=quad*4+reg
    #pragma unroll
    for (int i = 0; i < 4; ++i) {
        int mrow = m0 + wr + i * 16 + quad * 4;
        #pragma unroll
        for (int j = 0; j < 4; ++j) {
            int cgl = n0 + wc + j * 16 + l16;
            float bv = bias[cgl];
            #pragma unroll
            for (int r = 0; r < 4; ++r) {
                int m = mrow + r;
                float val = acc[i][j][r] + bv;
                if (MODE == 0) {
                    int which = cgl >> 9, hh = (cgl >> 6) & 7, hd = cgl & 63;
                    int b_ = m >> 12, n = m & 4095, bh = b_ * 8 + hh;
                    if (which == 0)      Qg[((size_t)bh * 4096 + n) * 64 + hd] = (bf16_t)val;
                    else if (which == 1) Kg[((size_t)bh * 4096 + n) * 64 + hd] = (bf16_t)val;
                    else                 Vt[((size_t)bh * 64 + hd) * 4096 + n] = (bf16_t)val;
                } else {
                    Cout[(size_t)m * 512 + cgl] = val;
                }
            }
        }
    }
}

// ---------------- flash attention ----------------
// grid = 16 bh * 64 q-tiles; block = 256 (4 waves, each wave owns a 16-row q stripe)

__global__ __launch_bounds__(256) void attn_kernel(
    const bf16_t* __restrict__ Qg, const bf16_t* __restrict__ Kg,
    const bf16_t* __restrict__ Vt, bf16_t* __restrict__ Og)
{
    __shared__ bf16_t Ks[64][72];        // [key][hd]
    __shared__ bf16_t Vs[64][72];        // [hd][key]  (V pre-transposed in global)
    __shared__ bf16_t Ps[4][16][72];     // per-wave P round-trip (C-layout -> A-layout)

    const int tid  = threadIdx.x;
    const int w    = tid >> 6, lane = tid & 63, l16 = lane & 15, quad = lane >> 4;
    const int bh   = blockIdx.x >> 6, qt = blockIdx.x & 63;

    const int qrow = qt * 64 + w * 16 + l16;
    const bf16_t* qp = Qg + ((size_t)bh * 4096 + qrow) * 64;
    bf16x8 qf0 = *(const bf16x8*)(qp + quad * 8);
    bf16x8 qf1 = *(const bf16x8*)(qp + 32 + quad * 8);

    f32x4 o[4] = {};
    float mrun[4], lrun[4];
    #pragma unroll
    for (int r = 0; r < 4; ++r) { mrun[r] = -1e30f; lrun[r] = 0.f; }
    const float sc = 0.125f * 1.4426950408889634f;   // scale * log2(e)

    for (int kt = 0; kt <= qt; ++kt) {
        __syncthreads();
        #pragma unroll
        for (int i = 0; i < 2; ++i) {
            int c = tid + i * 256, row = c >> 3, col8 = (c & 7) * 8;
            *(uint4*)&Ks[row][col8] = *(const uint4*)(Kg + ((size_t)bh * 4096 + kt * 64 + row) * 64 + col8);
            *(uint4*)&Vs[row][col8] = *(const uint4*)(Vt + ((size_t)bh * 64 + row) * 4096 + kt * 64 + col8);
        }
        __syncthreads();

        // S stripe: 16 q rows x 64 keys
        f32x4 s[4] = {};
        #pragma unroll
        for (int cb = 0; cb < 4; ++cb) {
            bf16x8 k0 = *(const bf16x8*)&Ks[cb * 16 + l16][quad * 8];
            bf16x8 k1 = *(const bf16x8*)&Ks[cb * 16 + l16][32 + quad * 8];
            s[cb] = __builtin_amdgcn_mfma_f32_16x16x32_bf16(qf0, k0, s[cb], 0, 0, 0);
            s[cb] = __builtin_amdgcn_mfma_f32_16x16x32_bf16(qf1, k1, s[cb], 0, 0, 0);
        }

        const int qbase = qt * 64 + w * 16 + quad * 4;
        #pragma unroll
        for (int cb = 0; cb < 4; ++cb)
            #pragma unroll
            for (int r = 0; r < 4; ++r) {
                float v = s[cb][r] * sc;
                if (kt == qt) {
                    int key = kt * 64 + cb * 16 + l16;
                    if (key > qbase + r) v = -1e30f;
                }
                s[cb][r] = v;
            }

        // online softmax (rows live on 16-lane groups: shuffle-xor 1,2,4,8)
        float alpha[4];
        #pragma unroll
        for (int r = 0; r < 4; ++r) {
            float v = fmaxf(fmaxf(s[0][r], s[1][r]), fmaxf(s[2][r], s[3][r]));
            v = fmaxf(v, __shfl_xor(v, 1));
            v = fmaxf(v, __shfl_xor(v, 2));
            v = fmaxf(v, __shfl_xor(v, 4));
            v = fmaxf(v, __shfl_xor(v, 8));
            float mn = fmaxf(mrun[r], v);
            alpha[r] = exp2f(mrun[r] - mn);
            mrun[r] = mn;
        }
        float ls[4] = {0.f, 0.f, 0.f, 0.f};
        #pragma unroll
        for (int cb = 0; cb < 4; ++cb)
            #pragma unroll
            for (int r = 0; r < 4; ++r) {
                float p = exp2f(s[cb][r] - mrun[r]);
                s[cb][r] = p;
                ls[r] += p;
            }
        #pragma unroll
        for (int r = 0; r < 4; ++r) {
            float v = ls[r];
            v += __shfl_xor(v, 1);
            v += __shfl_xor(v, 2);
            v += __shfl_xor(v, 4);
            v += __shfl_xor(v, 8);
            lrun[r] = lrun[r] * alpha[r] + v;
        }
        #pragma unroll
        for (int j = 0; j < 4; ++j)
            #pragma unroll
            for (int r = 0; r < 4; ++r) o[j][r] *= alpha[r];

        // P: C-layout -> LDS -> A-layout (per-wave private region, DS ops in-order per wave)
        #pragma unroll
        for (int cb = 0; cb < 4; ++cb)
            #pragma unroll
            for (int r = 0; r < 4; ++r)
                Ps[w][quad * 4 + r][cb * 16 + l16] = (bf16_t)s[cb][r];
        bf16x8 pa0 = *(const bf16x8*)&Ps[w][l16][quad * 8];
        bf16x8 pa1 = *(const bf16x8*)&Ps[w][l16][32 + quad * 8];

        #pragma unroll
        for (int j = 0; j < 4; ++j) {
            bf16x8 v0 = *(const bf16x8*)&Vs[j * 16 + l16][quad * 8];
            bf16x8 v1 = *(const bf16x8*)&Vs[j * 16 + l16][32 + quad * 8];
            o[j] = __builtin_amdgcn_mfma_f32_16x16x32_bf16(pa0, v0, o[j], 0, 0, 0);
            o[j] = __builtin_amdgcn_mfma_f32_16x16x32_bf16(pa1, v1, o[j], 0, 0, 0);
        }
    }

    // write O as [B][N][H*64] bf16 (row-major D) for the out-projection GEMM
    const int b_ = bh >> 3, hh = bh & 7;
    #pragma unroll
    for (int j = 0; j < 4; ++j)
        #pragma unroll
        for (int r = 0; r < 4; ++r) {
            int n = qt * 64 + w * 16 + quad * 4 + r;
            float val = o[j][r] / lrun[r];
            Og[((size_t)(b_ * 4096 + n)) * 512 + hh * 64 + j * 16 + l16] = (bf16_t)val;
        }
}

// ---------------- launch ----------------

extern "C" void kernel_launch(void* const* d_in, const int* in_sizes, int n_in,
                              void* d_out, int out_size, void* d_ws, size_t ws_size,
                              hipStream_t stream) {
    const float* x    = (const float*)d_in[0];   // [2,4096,512]
    const float* Wqkv = (const float*)d_in[1];   // [512,1536]
    const float* bqkv = (const float*)d_in[2];   // [1536]
    const float* Wout = (const float*)d_in[3];   // [512,512]
    const float* bout = (const float*)d_in[4];   // [512]
    float* out = (float*)d_out;                  // [2,4096,512] fp32

    char* ws = (char*)d_ws;
    // workspace layout (bytes)
    bf16_t* xb  = (bf16_t*)(ws);                 // 8192*512  = 8 MB  (reused as Og after QKV GEMM)
    bf16_t* WqT = (bf16_t*)(ws + 8388608);       // 1536*512  = 1.5 MB
    bf16_t* WoT = (bf16_t*)(ws + 9961472);       // 512*512   = 0.5 MB
    bf16_t* Qg  = (bf16_t*)(ws + 10485760);      // 16*4096*64 = 8 MB
    bf16_t* Kg  = (bf16_t*)(ws + 18874368);      // 8 MB
    bf16_t* Vt  = (bf16_t*)(ws + 27262976);      // 8 MB (transposed V: [bh][64][4096])

    convert_f32_bf16<<<4096, 256, 0, stream>>>(x, xb);                       // 8192*512/4 threads
    transpose_convert<<<3072, 256, 0, stream>>>(Wqkv, WqT, 1536);            // 1536*512 threads
    transpose_convert<<<1024, 256, 0, stream>>>(Wout, WoT, 512);             // 512*512 threads

    gemm_bt<0><<<dim3(12, 64), 256, 0, stream>>>(xb, WqT, bqkv, Qg, Kg, Vt, nullptr);

    attn_kernel<<<1024, 256, 0, stream>>>(Qg, Kg, Vt, xb /* reuse as Og */);

    gemm_bt<1><<<dim3(4, 64), 256, 0, stream>>>(xb, WoT, bout, nullptr, nullptr, nullptr, out);
}